// Round 6
// baseline (263.409 us; speedup 1.0000x reference)
//
#include <hip/hip_runtime.h>
#include <math.h>

#define LEVELS 16
#define FEAT 2

// Ns[l] = python round(16 * 1.5^l)  (banker's rounding; exact in fp32)
__constant__ float c_Ns[LEVELS] = {
    16.f, 24.f, 36.f, 54.f, 81.f, 122.f, 182.f, 273.f,
    410.f, 615.f, 923.f, 1384.f, 2076.f, 3114.f, 4671.f, 7006.f
};

#define P1 2654435761u
#define P2 805459861u

// Compute hash indices + issue the 16 gathers for level-group G into buffer BUF.
// All array indices are compile-time constants (G, BUF literals; k unrolled).
#define LOADG(G, BUF)                                                          \
  {                                                                            \
    _Pragma("unroll") for (int k = 0; k < 4; ++k) {                            \
      const int l = (G) * 4 + k;                                               \
      const float s = sc[l];                                                   \
      const float xs = px * s, ys = py * s;                                    \
      const float fx0f = floorf(xs), fy0f = floorf(ys);                        \
      fxb[BUF][k] = xs - fx0f;                                                 \
      fyb[BUF][k] = ys - fy0f;                                                 \
      const unsigned int ux = (unsigned int)(int)fx0f;                         \
      const unsigned int uy = (unsigned int)(int)fy0f;                         \
      const unsigned int sd = sds[l];                                          \
      const unsigned int ax0 = ux * P1;                                        \
      const unsigned int ax1 = ax0 + P1; /* (ux+1)*P1 mod 2^32 */              \
      const unsigned int ay0 = (uy * P2) ^ sd;                                 \
      const unsigned int ay1 = (uy * P2 + P2) ^ sd;                            \
      unsigned int i00, i10, i01, i11;                                         \
      if (POW2_TABLE) {                                                        \
        i00 = (ax0 ^ ay0) & tmask;                                             \
        i10 = (ax1 ^ ay0) & tmask;                                             \
        i01 = (ax0 ^ ay1) & tmask;                                             \
        i11 = (ax1 ^ ay1) & tmask;                                             \
      } else {                                                                 \
        i00 = (ax0 ^ ay0) % tsize;                                             \
        i10 = (ax1 ^ ay0) % tsize;                                             \
        i01 = (ax0 ^ ay1) % tsize;                                             \
        i11 = (ax1 ^ ay1) % tsize;                                             \
      }                                                                        \
      fb[BUF][k][0] = tables[i00];                                             \
      fb[BUF][k][1] = tables[i10];                                             \
      fb[BUF][k][2] = tables[i01];                                             \
      fb[BUF][k][3] = tables[i11];                                             \
    }                                                                          \
  }

// Consume buffer BUF for level-group G: bilinear lerp + nontemporal stores.
#define MATHG(G, BUF)                                                          \
  {                                                                            \
    _Pragma("unroll") for (int k = 0; k < 4; ++k) {                            \
      const int l = (G) * 4 + k;                                               \
      const float fx = fxb[BUF][k], fy = fyb[BUF][k];                          \
      const float omx = 1.0f - fx, omy = 1.0f - fy;                            \
      const float w00 = omx * omy, w10 = fx * omy;                             \
      const float w01 = omx * fy, w11 = fx * fy;                               \
      const float2 f00 = fb[BUF][k][0], f10 = fb[BUF][k][1];                   \
      const float2 f01 = fb[BUF][k][2], f11 = fb[BUF][k][3];                   \
      const float e0 = w00 * f00.x + w10 * f10.x + w01 * f01.x + w11 * f11.x;  \
      const float e1 = w00 * f00.y + w10 * f10.y + w01 * f01.y + w11 * f11.y;  \
      __builtin_nontemporal_store(e0, outb + (size_t)(2 * l) * (size_t)N);     \
      __builtin_nontemporal_store(e1, outb + (size_t)(2 * l + 1) * (size_t)N); \
    }                                                                          \
  }

// Pin pipeline stage order: loads issued before this fence may not be sunk
// past it by the LLVM scheduler (which otherwise minimizes VGPR by placing
// each gather just before its use — the round-4 VGPR=32 latency trap).
#define FENCE() __builtin_amdgcn_sched_barrier(0)

template <bool POW2_TABLE, bool POW2_W>
__global__ __launch_bounds__(256) void hashenc_kernel(
    const float* __restrict__ x0,
    const float* __restrict__ y0,
    const float2* __restrict__ tables,
    const unsigned int* __restrict__ seeds,
    const int* __restrict__ tile_ptr,
    float* __restrict__ out,
    int N,              // H*W
    int W,              // row width
    int wshift,         // log2(W) when POW2_W
    unsigned int tsize, // table size (elements)
    unsigned int tmask) // tsize-1 when POW2_TABLE
{
    const int pix = blockIdx.x * blockDim.x + threadIdx.x;
    if (pix >= N) return;
    const int b = blockIdx.y;

    int i, j;
    if (POW2_W) {
        i = pix >> wshift;
        j = pix & (W - 1);
    } else {
        i = pix / W;
        j = pix - i * W;
    }

    // Uniform seed loads -> SGPRs
    unsigned int sds[LEVELS];
#pragma unroll
    for (int l = 0; l < LEVELS; ++l) sds[l] = seeds[l];

    // Reference computes scales = Ns / float(tile) in f32. Pow2 tile ->
    // reciprocal path is bit-exact; otherwise true f32 division (a 1-ULP
    // scale wobble can flip floorf at a cell boundary -> different hash).
    const int tile = *tile_ptr; // uniform
    const float tilef = (float)tile;
    float sc[LEVELS];
    if ((tile & (tile - 1)) == 0) {
        const float inv_tile = 1.0f / tilef;
#pragma unroll
        for (int l = 0; l < LEVELS; ++l) sc[l] = c_Ns[l] * inv_tile;
    } else {
#pragma unroll
        for (int l = 0; l < LEVELS; ++l) sc[l] = c_Ns[l] / tilef;
    }

    const float px = (float)j + x0[b];
    const float py = (float)i + y0[b];

    // out[b][l*2+f][pix], channel stride N
    float* outb = out + (size_t)b * (size_t)(LEVELS * FEAT) * (size_t)N + pix;

    // Depth-2 software pipeline over 4 level-groups: 32 gathers in flight at
    // steady state (vs ~4 when the compiler minimized registers to 32 VGPR).
    float2 fb[2][4][4];   // [buf][k][corner] — all static indices
    float fxb[2][4], fyb[2][4];

    LOADG(0, 0)
    LOADG(1, 1)
    FENCE();
    MATHG(0, 0)
    LOADG(2, 0)
    FENCE();
    MATHG(1, 1)
    LOADG(3, 1)
    FENCE();
    MATHG(2, 0)
    MATHG(3, 1)
}

extern "C" void kernel_launch(void* const* d_in, const int* in_sizes, int n_in,
                              void* d_out, int out_size, void* d_ws, size_t ws_size,
                              hipStream_t stream) {
    const float* x0 = (const float*)d_in[0];
    const float* y0 = (const float*)d_in[1];
    const float2* tables = (const float2*)d_in[2];
    const unsigned int* seeds = (const unsigned int*)d_in[3];
    // d_in[4] = memorized_crop_size (device scalar; geometry derived from out_size)
    const int* tile_ptr = (const int*)d_in[5];

    const int Bn = in_sizes[0];
    const unsigned int tsize = (unsigned int)(in_sizes[2] / FEAT);
    const int N = out_size / (Bn * LEVELS * FEAT);       // H*W
    const int W = (int)(sqrt((double)N) + 0.5);          // H == W in reference
    int wshift = 0;
    while ((1 << wshift) < W) ++wshift;

    float* out = (float*)d_out;

    dim3 grid((N + 255) / 256, Bn);
    dim3 block(256);

    const bool pow2_table = (tsize & (tsize - 1)) == 0;
    const bool pow2_w = (W & (W - 1)) == 0;

    if (pow2_table && pow2_w) {
        hashenc_kernel<true, true><<<grid, block, 0, stream>>>(
            x0, y0, tables, seeds, tile_ptr, out, N, W, wshift, tsize, tsize - 1u);
    } else if (pow2_table) {
        hashenc_kernel<true, false><<<grid, block, 0, stream>>>(
            x0, y0, tables, seeds, tile_ptr, out, N, W, wshift, tsize, tsize - 1u);
    } else if (pow2_w) {
        hashenc_kernel<false, true><<<grid, block, 0, stream>>>(
            x0, y0, tables, seeds, tile_ptr, out, N, W, wshift, tsize, 0u);
    } else {
        hashenc_kernel<false, false><<<grid, block, 0, stream>>>(
            x0, y0, tables, seeds, tile_ptr, out, N, W, wshift, tsize, 0u);
    }
}